// Round 1
// baseline (9507.134 us; speedup 1.0000x reference)
//
#include <hip/hip_runtime.h>
#include <hip/hip_bf16.h>
#include <math.h>

#define BB   64
#define INP  1024
#define HIDN 2048
#define NPU  256
#define MEMN 4096
#define RR   512
#define DD   512
#define MMU_USED 1537   // 3*D + 1 gate col; remaining 1027 rows of mmu_w are unused by reference

// ---- workspace layout (float units; bf16 block at end) ----
#define OFF_QUERY  ((size_t)0)
#define OFF_WKEY   (OFF_QUERY + (size_t)BB*NPU*DD)
#define OFF_WVAL   (OFF_WKEY  + (size_t)BB*NPU*DD)
#define OFF_RDATA  (OFF_WVAL  + (size_t)BB*NPU*DD)
#define OFF_WGATE  (OFF_RDATA + (size_t)BB*NPU*DD)
#define OFF_WMAX   (OFF_WGATE + (size_t)BB*NPU)
#define OFF_WSUM   (OFF_WMAX  + (size_t)BB*NPU)
#define OFF_GIX    (OFF_WSUM  + (size_t)BB*NPU)
#define OFF_P      (OFF_GIX   + (size_t)BB*1536)
#define OFF_R      (OFF_P     + 1024)
#define OFF_FEND   (OFF_R     + 512)
// swsc (bf16 write scores, B*NPU*MEMN elems) at byte offset OFF_FEND*4

__device__ __forceinline__ float dot4(float4 a, float4 b) {
    return a.x*b.x + a.y*b.y + a.z*b.z + a.w*b.w;
}

// p[i] = sum_h agg_q[h] * proj_w[h,i]
__global__ __launch_bounds__(256) void kP0(const float* __restrict__ proj_w,
                                           const float* __restrict__ agg_q,
                                           float* __restrict__ p) {
    int i = blockIdx.x * 256 + threadIdx.x;      // < 1024
    float acc = 0.f;
    for (int h = 0; h < HIDN; ++h) acc += agg_q[h] * proj_w[(size_t)h * INP + i];
    p[i] = acc;
}

// r[j] = sum_i p[i] * out_w[i,j]
__global__ __launch_bounds__(256) void kP1(const float* __restrict__ out_w,
                                           const float* __restrict__ p,
                                           float* __restrict__ r) {
    int j = blockIdx.x * 256 + threadIdx.x;      // < 512
    float acc = 0.f;
    for (int i = 0; i < INP; ++i) acc += p[i] * out_w[(size_t)i * RR + j];
    r[j] = acc;
}

// pass-through copy hidden_state -> out hidden region (rows >= A keep original)
__global__ __launch_bounds__(256) void kCopyHidden(const float4* __restrict__ src,
                                                   float4* __restrict__ dst) {
    int idx = blockIdx.x * 256 + threadIdx.x;    // grid 2048 -> 524288 threads
#pragma unroll
    for (int j = 0; j < 4; ++j) dst[idx + j * 524288] = src[idx + j * 524288];
}

// gix[b,n] = b_ih[n] + sum_{i<1024} x[b,i]*W_ih[n,i]   (x part of GRU input GEMM, per-b only)
__global__ __launch_bounds__(256) void kGix(const float* __restrict__ x,
                                            const float* __restrict__ w_ih,
                                            const float* __restrict__ b_ih,
                                            float* __restrict__ gix) {
    int b = blockIdx.x;
    int n = blockIdx.y * 256 + threadIdx.x;      // < 1536
    __shared__ __align__(16) float xs[INP];
    for (int i = threadIdx.x; i < INP; i += 256) xs[i] = x[(size_t)b * INP + i];
    __syncthreads();
    const float4* w  = (const float4*)(w_ih + (size_t)n * 1536);
    const float4* xv = (const float4*)xs;
    float acc = 0.f;
    for (int kc = 0; kc < 256; ++kc) acc += dot4(w[kc], xv[kc]);
    gix[(size_t)b * 1536 + n] = acc + b_ih[n];
}

// mmu GEMM: (16 NPUs per block) x 1537 used output rows
__global__ __launch_bounds__(256) void kMmu(const float* __restrict__ hidden,
                                            const float* __restrict__ mmu_w,
                                            const float* __restrict__ mmu_b,
                                            float* __restrict__ query, float* __restrict__ wkey,
                                            float* __restrict__ wval,  float* __restrict__ wgate,
                                            const int* __restrict__ anp) {
    int b = blockIdx.x, at = blockIdx.y, t = threadIdx.x;
    int A = *anp;
    int a0 = at * 16;
    __shared__ __align__(16) float regs[16 * RR];
    const float4* src = (const float4*)(hidden + ((size_t)b * NPU + a0) * RR);
#pragma unroll
    for (int j = 0; j < 8; ++j) ((float4*)regs)[t + j * 256] = src[t + j * 256];
    __syncthreads();
    for (int n = t; n < MMU_USED; n += 256) {
        const float4* w = (const float4*)(mmu_w + (size_t)n * RR);
        float acc[16];
#pragma unroll
        for (int a = 0; a < 16; ++a) acc[a] = 0.f;
        for (int kc = 0; kc < 128; ++kc) {
            float4 wv = w[kc];
#pragma unroll
            for (int a = 0; a < 16; ++a)
                acc[a] += dot4(wv, ((const float4*)regs)[a * 128 + kc]);  // LDS broadcast
        }
        float bias = mmu_b[n];
#pragma unroll
        for (int a = 0; a < 16; ++a) {
            int aa = a0 + a;
            if (aa >= A) continue;
            float v = acc[a] + bias;
            size_t base = (size_t)b * NPU + aa;
            if (n < 512)       query[base * DD + n] = v;
            else if (n < 1024) wkey [base * DD + n - 512] = v;
            else if (n < 1536) wval [base * DD + n - 1024] = v;
            else               wgate[base] = 1.f / (1.f + __expf(-v));
        }
    }
}

// ============================================================================
// MFMA flash attention (read scores + write-score stats), bf16 matrix cores.
//
// Block: 512 threads = 8 waves; handles 64 NPUs (grid 4 x B). One block/CU.
// Per 64-row mem tile:
//   stage: fp32 mem -> bf16 LDS in TWO layouts (row-major for score A-operand,
//          transposed for PV B-operand), both XOR-swizzled for bank spread.
//   waves 0-3: S^T = M x Qs^T for 16 a's each  (lane's 16 scores are ONE a ->
//              online softmax = local max + 2 shfl_xor; P -> bf16 -> LDS)
//   waves 4-7: Sw^T = M x Ks^T, online (max,sum), bf16 score store to swsc.
//   all 8:     PV d-slice (64 cols each) via MFMA, with scale-rescale skip flag.
// 1/sqrt(512) folded into the bf16 conversion of Q/K.
// Raw s_barrier + manual lgkmcnt (no vmcnt drain) so next-tile global loads
// stay in flight across barriers (async staging).
// ============================================================================

typedef __bf16 bf16_t;
typedef bf16_t bf16x8 __attribute__((ext_vector_type(8)));
typedef unsigned short u16x8 __attribute__((ext_vector_type(8)));
typedef unsigned short u16x4 __attribute__((ext_vector_type(4)));
typedef float f32x4 __attribute__((ext_vector_type(4)));

__device__ __forceinline__ unsigned short f2bf(float f) {
    unsigned u = __builtin_bit_cast(unsigned, f);
    unsigned r = u + 0x7FFFu + ((u >> 16) & 1u);   // RNE, matches __float2bfloat16
    return (unsigned short)(r >> 16);
}

#define LDSOFF_MROW 0        // 64 rows x 1024B  (bf16 [m][d]), swz ^((m&7)<<4)
#define LDSOFF_MT   65536    // 512 rows x 128B  (bf16 [d][m]), swz ^((((d>>3)^d)&7)<<4)
#define LDSOFF_P    131072   // 64 rows x 128B   (bf16 [a][m]), swz ^((a&7)<<4)
#define LDSOFF_SCL  139264   // 64 f32 rescale factors
#define LDSOFF_LFIN 139520   // 64 f32 final softmax denominators
#define LDSOFF_FLG  139776   // 4 ints rescale-needed flags
#define LDS_TOTAL   139808

#define BARRIER_LDS() do { \
    asm volatile("s_waitcnt lgkmcnt(0)" ::: "memory"); \
    __builtin_amdgcn_sched_barrier(0); \
    __builtin_amdgcn_s_barrier(); \
    asm volatile("" ::: "memory"); \
    __builtin_amdgcn_sched_barrier(0); \
} while (0)

__global__ __launch_bounds__(512, 2) void kAttnMfma(
    const float* __restrict__ mem,
    const float* __restrict__ query,
    const float* __restrict__ wkey,
    float* __restrict__ rdata,
    unsigned short* __restrict__ swsc,
    float* __restrict__ wmax, float* __restrict__ wsum,
    const int* __restrict__ anp)
{
    __shared__ __align__(16) char smem[LDS_TOTAL];
    const int A   = *anp;
    const int b   = blockIdx.y;
    const int Ab0 = blockIdx.x * 64;
    if (Ab0 >= A) return;

    const int t    = threadIdx.x;
    const int wv   = t >> 6;         // wave 0..7
    const int lane = t & 63;
    const int r    = lane & 15;      // MFMA row/col lane index
    const int g    = lane >> 4;      // MFMA k-group
    const bool isS = (wv < 4);
    const int aBase = (isS ? wv : wv - 4) << 4;   // wave's 16-NPU slice (rel.)
    const float inv = 0.044194173824159216f;      // 1/sqrt(512)

    const float* mrow_base = mem + (size_t)b * MEMN * DD;

    // ---- issue staging loads for tile 0 (rows 8*wv+i, cols 8*lane..) ----
    float4 stg[16];
    {
        const float4* sp = (const float4*)(mrow_base + (size_t)(8 * wv) * DD) + lane * 2;
#pragma unroll
        for (int i = 0; i < 8; ++i) { stg[2*i] = sp[i*128]; stg[2*i+1] = sp[i*128+1]; }
    }

    // ---- Q/K fragments, scaled by inv, held in registers (64 VGPR) ----
    // B-frag layout: lane holds col a=(lane&15), k = kk*32 + 8*(lane>>4) + j
    bf16x8 qf[16];
    {
        const int aG = Ab0 + aBase + r;
        const bool act = (aG < A);
        const float* qsrc = (isS ? query : wkey) + ((size_t)b * NPU + aG) * DD + 8 * g;
#pragma unroll
        for (int kk = 0; kk < 16; ++kk) {
            float4 v0 = make_float4(0.f,0.f,0.f,0.f), v1 = make_float4(0.f,0.f,0.f,0.f);
            if (act) {
                const float4* p4 = (const float4*)(qsrc + kk * 32);
                v0 = p4[0]; v1 = p4[1];
            }
            u16x8 uv = { f2bf(v0.x*inv), f2bf(v0.y*inv), f2bf(v0.z*inv), f2bf(v0.w*inv),
                         f2bf(v1.x*inv), f2bf(v1.y*inv), f2bf(v1.z*inv), f2bf(v1.w*inv) };
            qf[kk] = __builtin_bit_cast(bf16x8, uv);
        }
    }

    float* scl_lds  = (float*)(smem + LDSOFF_SCL);
    float* lfin_lds = (float*)(smem + LDSOFF_LFIN);
    int*   flg_lds  = (int*)(smem + LDSOFF_FLG);

    // PV accumulator: rows a = as*16 + 4g + reg, col d = wv*64 + ds*16 + r
    f32x4 pacc[4][4];
    {
        f32x4 z = {0.f, 0.f, 0.f, 0.f};
#pragma unroll
        for (int i = 0; i < 4; ++i)
#pragma unroll
            for (int j = 0; j < 4; ++j) pacc[i][j] = z;
    }
    float mrun = -INFINITY, lrun = 0.f;

    for (int tt = 0; tt < MEMN / 64; ++tt) {
        const int m0 = tt * 64;

        // ===== stage: cvt + dual-layout LDS write (tile tt) =====
        unsigned short bv[8][8];
#pragma unroll
        for (int i = 0; i < 8; ++i) {
            float4 lo = stg[2*i], hi = stg[2*i+1];
            bv[i][0]=f2bf(lo.x); bv[i][1]=f2bf(lo.y); bv[i][2]=f2bf(lo.z); bv[i][3]=f2bf(lo.w);
            bv[i][4]=f2bf(hi.x); bv[i][5]=f2bf(hi.y); bv[i][6]=f2bf(hi.z); bv[i][7]=f2bf(hi.w);
            int m = 8 * wv + i;
            int byte = (m << 10) + (lane << 4);
            byte ^= (m & 7) << 4;
            u16x8 rv = { bv[i][0],bv[i][1],bv[i][2],bv[i][3],bv[i][4],bv[i][5],bv[i][6],bv[i][7] };
            *(u16x8*)(smem + LDSOFF_MROW + byte) = rv;
        }
#pragma unroll
        for (int j = 0; j < 8; ++j) {
            int d = 8 * lane + j;
            int byte = (d << 7) + (wv << 4);
            byte ^= (((d >> 3) ^ d) & 7) << 4;
            u16x8 cv = { bv[0][j],bv[1][j],bv[2][j],bv[3][j],bv[4][j],bv[5][j],bv[6][j],bv[7][j] };
            *(u16x8*)(smem + LDSOFF_MT + byte) = cv;
        }
        // issue next tile's loads (kept in flight across raw barriers)
        if (tt + 1 < MEMN / 64) {
            const float4* sp = (const float4*)(mrow_base + (size_t)((tt+1)*64 + 8*wv) * DD) + lane * 2;
#pragma unroll
            for (int i = 0; i < 8; ++i) { stg[2*i] = sp[i*128]; stg[2*i+1] = sp[i*128+1]; }
        }
        BARRIER_LDS();

        // ===== phase B: scores S^T (or Sw^T), 64m x 16a per wave =====
        f32x4 sacc[4];
        {
            f32x4 z = {0.f, 0.f, 0.f, 0.f};
            sacc[0] = z; sacc[1] = z; sacc[2] = z; sacc[3] = z;
        }
#pragma unroll
        for (int kk = 0; kk < 16; ++kk) {
#pragma unroll
            for (int ms = 0; ms < 4; ++ms) {
                int m = ms * 16 + r;
                int byte = (m << 10) + (kk << 6) + (g << 4);
                byte ^= (m & 7) << 4;
                bf16x8 af = *(const bf16x8*)(smem + LDSOFF_MROW + byte);
                sacc[ms] = __builtin_amdgcn_mfma_f32_16x16x32_bf16(af, qf[kk], sacc[ms], 0, 0, 0);
            }
        }
        // lane's 16 scores all belong to a = aBase + r, m = m0 + ms*16 + 4g + reg
        float tmax = -INFINITY;
#pragma unroll
        for (int ms = 0; ms < 4; ++ms)
            tmax = fmaxf(tmax, fmaxf(fmaxf(sacc[ms][0], sacc[ms][1]),
                                     fmaxf(sacc[ms][2], sacc[ms][3])));
        tmax = fmaxf(tmax, __shfl_xor(tmax, 16));
        tmax = fmaxf(tmax, __shfl_xor(tmax, 32));
        float mnew = fmaxf(mrun, tmax);
        float sclf = __expf(mrun - mnew);
        float lsum = 0.f;
        if (isS) {
            int aRel = aBase + r;
#pragma unroll
            for (int ms = 0; ms < 4; ++ms) {
                float p0 = __expf(sacc[ms][0] - mnew), p1 = __expf(sacc[ms][1] - mnew);
                float p2 = __expf(sacc[ms][2] - mnew), p3 = __expf(sacc[ms][3] - mnew);
                lsum += (p0 + p1) + (p2 + p3);
                u16x4 pk = { f2bf(p0), f2bf(p1), f2bf(p2), f2bf(p3) };
                int byte = (aRel << 7) + (ms << 5) + (g << 3);
                byte ^= (r & 7) << 4;
                *(u16x4*)(smem + LDSOFF_P + byte) = pk;
            }
            if (lane < 16) scl_lds[aBase + lane] = sclf;
            int fneed = __any(sclf != 1.f);
            if (lane == 0) flg_lds[wv] = fneed;
        } else {
            int aG = Ab0 + aBase + r;
#pragma unroll
            for (int ms = 0; ms < 4; ++ms) {
                lsum += (__expf(sacc[ms][0] - mnew) + __expf(sacc[ms][1] - mnew))
                      + (__expf(sacc[ms][2] - mnew) + __expf(sacc[ms][3] - mnew));
            }
            if (aG < A) {
                size_t sb = ((size_t)b * NPU + aG) * MEMN + m0 + 4 * g;
#pragma unroll
                for (int ms = 0; ms < 4; ++ms) {
                    u16x4 sv = { f2bf(sacc[ms][0]), f2bf(sacc[ms][1]),
                                 f2bf(sacc[ms][2]), f2bf(sacc[ms][3]) };
                    *(u16x4*)(swsc + sb + ms * 16) = sv;
                }
            }
        }
        lsum += __shfl_xor(lsum, 16);
        lsum += __shfl_xor(lsum, 32);
        lrun = lrun * sclf + lsum;
        mrun = mnew;
        BARRIER_LDS();

        // ===== phase C: PV accumulate (all 8 waves, d-slice 64 each) =====
        int f = flg_lds[0] | flg_lds[1] | flg_lds[2] | flg_lds[3];
        if (f) {
#pragma unroll
            for (int as = 0; as < 4; ++as)
#pragma unroll
                for (int rg = 0; rg < 4; ++rg) {
                    float sc = scl_lds[as * 16 + 4 * g + rg];
#pragma unroll
                    for (int ds = 0; ds < 4; ++ds) pacc[as][ds][rg] *= sc;
                }
        }
#pragma unroll
        for (int as = 0; as < 4; ++as) {
            int ar = as * 16 + r;
            int ab0 = ((ar << 7) + (g << 4)) ^ ((r & 7) << 4);
            int ab1 = ((ar << 7) + 64 + (g << 4)) ^ ((r & 7) << 4);
            bf16x8 pa0 = *(const bf16x8*)(smem + LDSOFF_P + ab0);
            bf16x8 pa1 = *(const bf16x8*)(smem + LDSOFF_P + ab1);
#pragma unroll
            for (int ds = 0; ds < 4; ++ds) {
                int d = (wv << 6) + (ds << 4) + r;
                int key = (((d >> 3) ^ d) & 7) << 4;
                int mb0 = ((d << 7) + (g << 4)) ^ key;
                int mb1 = ((d << 7) + 64 + (g << 4)) ^ key;
                bf16x8 bm0 = *(const bf16x8*)(smem + LDSOFF_MT + mb0);
                bf16x8 bm1 = *(const bf16x8*)(smem + LDSOFF_MT + mb1);
                pacc[as][ds] = __builtin_amdgcn_mfma_f32_16x16x32_bf16(pa0, bm0, pacc[as][ds], 0, 0, 0);
                pacc[as][ds] = __builtin_amdgcn_mfma_f32_16x16x32_bf16(pa1, bm1, pacc[as][ds], 0, 0, 0);
            }
        }
        BARRIER_LDS();
    }

    // ===== epilogue =====
    if (isS) {
        if (lane < 16) lfin_lds[aBase + lane] = lrun;
    } else if (lane < 16) {
        int aG = Ab0 + aBase + lane;
        if (aG < A) {
            wmax[(size_t)b * NPU + aG] = mrun;
            wsum[(size_t)b * NPU + aG] = lrun;
        }
    }
    BARRIER_LDS();
#pragma unroll
    for (int as = 0; as < 4; ++as)
#pragma unroll
        for (int rg = 0; rg < 4; ++rg) {
            int aRel = as * 16 + 4 * g + rg;
            int aG = Ab0 + aRel;
            if (aG < A) {
                float invl = 1.f / lfin_lds[aRel];
#pragma unroll
                for (int ds = 0; ds < 4; ++ds) {
                    int d = (wv << 6) + (ds << 4) + r;
                    rdata[((size_t)b * NPU + aG) * DD + d] = pacc[as][ds][rg] * invl;
                }
            }
        }
}

// GRU cell, 16 a's per block, thread owns j and j+256
__global__ __launch_bounds__(256) void kGru(const float* __restrict__ hidden,
                                            const float* __restrict__ rdata,
                                            const float* __restrict__ w_ih,
                                            const float* __restrict__ w_hh,
                                            const float* __restrict__ b_hh,
                                            const float* __restrict__ gix,
                                            float* __restrict__ out_hidden,
                                            const int* __restrict__ anp) {
    int b = blockIdx.x, at = blockIdx.y, t = threadIdx.x;
    int A = *anp;
    int a0 = at * 16;
    __shared__ __align__(16) float rd[16 * RR];
    __shared__ __align__(16) float hh[16 * RR];
    const float4* s1 = (const float4*)(rdata  + ((size_t)b * NPU + a0) * DD);
    const float4* s2 = (const float4*)(hidden + ((size_t)b * NPU + a0) * RR);
#pragma unroll
    for (int j = 0; j < 8; ++j) {
        ((float4*)rd)[t + j * 256] = s1[t + j * 256];
        ((float4*)hh)[t + j * 256] = s2[t + j * 256];
    }
    __syncthreads();
#pragma unroll 1
    for (int jj = 0; jj < 2; ++jj) {
        int j = t + jj * 256;
        float rv[16], zv[16];
#pragma unroll 1
        for (int gate = 0; gate < 3; ++gate) {
            int n = gate * RR + j;
            const float4* wi = (const float4*)(w_ih + (size_t)n * 1536 + 1024);
            const float4* wh = (const float4*)(w_hh + (size_t)n * RR);
            float ai[16], ah[16];
#pragma unroll
            for (int a = 0; a < 16; ++a) { ai[a] = 0.f; ah[a] = 0.f; }
            for (int kc = 0; kc < 128; ++kc) {
                float4 wiv = wi[kc];
                float4 whv = wh[kc];
#pragma unroll
                for (int a = 0; a < 16; ++a) {
                    ai[a] += dot4(wiv, ((const float4*)rd)[a * 128 + kc]);
                    ah[a] += dot4(whv, ((const float4*)hh)[a * 128 + kc]);
                }
            }
            float gx = gix[(size_t)b * 1536 + n];
            float bh = b_hh[n];
            if (gate == 0) {
#pragma unroll
                for (int a = 0; a < 16; ++a) rv[a] = 1.f / (1.f + __expf(-(ai[a] + gx + ah[a] + bh)));
            } else if (gate == 1) {
#pragma unroll
                for (int a = 0; a < 16; ++a) zv[a] = 1.f / (1.f + __expf(-(ai[a] + gx + ah[a] + bh)));
            } else {
#pragma unroll
                for (int a = 0; a < 16; ++a) {
                    int aa = a0 + a;
                    if (aa >= A) continue;
                    float nn = tanhf(ai[a] + gx + rv[a] * (ah[a] + bh));
                    float h = hh[a * RR + j];
                    out_hidden[((size_t)b * NPU + aa) * RR + j] = (1.f - zv[a]) * nn + zv[a] * h;
                }
            }
        }
    }
}

// write attention combine + memory update. 16 m rows per block.
#define MT 16
__global__ __launch_bounds__(256) void kWrite(const float* __restrict__ mem,
                                              const float* __restrict__ wval,
                                              const float* __restrict__ wgate,
                                              const float* __restrict__ wmax,
                                              const float* __restrict__ wsum,
                                              const __hip_bfloat16* __restrict__ swsc,
                                              float* __restrict__ out_mem,
                                              const int* __restrict__ anp) {
    int b = blockIdx.x, mtile = blockIdx.y, t = threadIdx.x;
    int A = *anp;
    int m0 = mtile * MT;
    __shared__ __align__(16) float cL[NPU * MT];
    __shared__ float ec[NPU], wm[NPU];
    __shared__ float twL[MT];
    __shared__ __align__(16) float cv[MT * 516];   // pitch 516 floats (2064B, 16B aligned)
    {
        int a = t;
        float e = 0.f, w = 0.f;
        if (a < A) {
            e = wgate[(size_t)b * NPU + a] / wsum[(size_t)b * NPU + a];
            w = wmax[(size_t)b * NPU + a];
        }
        ec[a] = e; wm[a] = w;
    }
    __syncthreads();
#pragma unroll
    for (int i = 0; i < MT; ++i) {
        int flat = t + i * 256;          // flat = a*MT + mi
        int a = flat >> 4, mi = flat & 15;
        float s = __bfloat162float(swsc[((size_t)b * NPU + a) * MEMN + m0 + mi]);
        cL[flat] = ec[a] * __expf(s - wm[a]);
    }
    __syncthreads();
    int mi = t & 15, dg = t >> 4;        // d slice = dg*32 .. +31
    float acc[32];
#pragma unroll
    for (int i = 0; i < 32; ++i) acc[i] = 0.f;
    float tws = 0.f;
    for (int a = 0; a < NPU; ++a) {
        float ca = cL[a * MT + mi];
        tws += ca;
        const float4* wr = (const float4*)(wval + ((size_t)b * NPU + a) * DD + dg * 32);
#pragma unroll
        for (int i = 0; i < 8; ++i) {
            float4 v = wr[i];
            acc[4*i]   += ca * v.x; acc[4*i+1] += ca * v.y;
            acc[4*i+2] += ca * v.z; acc[4*i+3] += ca * v.w;
        }
    }
    if (t < MT) twL[t] = fminf(fmaxf(tws, 0.f), 1.f);
#pragma unroll
    for (int i = 0; i < 8; ++i)
        *(float4*)&cv[mi * 516 + dg * 32 + 4 * i] =
            make_float4(acc[4*i], acc[4*i+1], acc[4*i+2], acc[4*i+3]);
    __syncthreads();
    const float4* min4 = (const float4*)(mem     + ((size_t)b * MEMN + m0) * DD);
    float4*      mout4 = (float4*)      (out_mem + ((size_t)b * MEMN + m0) * DD);
#pragma unroll
    for (int i = 0; i < 8; ++i) {
        int f4 = t + i * 256;
        int row = f4 >> 7, col = (f4 & 127) * 4;
        float tw = twL[row];
        float4 mv = min4[f4];
        float4 cvv = *(const float4*)&cv[row * 516 + col];
        mout4[f4] = make_float4(mv.x * (1.f - tw) + cvv.x, mv.y * (1.f - tw) + cvv.y,
                                mv.z * (1.f - tw) + cvv.z, mv.w * (1.f - tw) + cvv.w);
    }
}

__device__ __forceinline__ float blockSum(float v, float* red, int t) {
#pragma unroll
    for (int off = 32; off >= 1; off >>= 1) v += __shfl_xor(v, off);
    __syncthreads();
    if ((t & 63) == 0) red[t >> 6] = v;
    __syncthreads();
    return red[0] + red[1] + red[2] + red[3];
}
__device__ __forceinline__ float blockMax(float v, float* red, int t) {
#pragma unroll
    for (int off = 32; off >= 1; off >>= 1) v = fmaxf(v, __shfl_xor(v, off));
    __syncthreads();
    if ((t & 63) == 0) red[t >> 6] = v;
    __syncthreads();
    return fmaxf(fmaxf(red[0], red[1]), fmaxf(red[2], red[3]));
}

// collapsed output head: softmax over a of r.new_regs, then proj(out(u)), then LN
__global__ __launch_bounds__(256) void kOut(const float* __restrict__ nr,
                                            const float* __restrict__ rvec,
                                            const float* __restrict__ out_w,
                                            const float* __restrict__ out_b,
                                            const float* __restrict__ proj_w,
                                            const float* __restrict__ proj_b,
                                            const float* __restrict__ ln_g,
                                            const float* __restrict__ ln_b,
                                            float* __restrict__ out,
                                            const int* __restrict__ anp) {
    int b = blockIdx.x, t = threadIdx.x;
    int A = *anp;
    __shared__ float sa[NPU];
    __shared__ __align__(16) float uL[RR];
    __shared__ __align__(16) float npuL[INP];
    __shared__ float red[4];
    __shared__ float aggS[HIDN];
    const float inv_h = 0.022097086912079608f;  // 1/sqrt(2048)
    float s = -INFINITY;
    if (t < A) {
        const float4* row = (const float4*)(nr + ((size_t)b * NPU + t) * RR);
        const float4* rv4 = (const float4*)rvec;
        float acc = 0.f;
        for (int i = 0; i < 128; ++i) acc += dot4(row[i], rv4[i]);
        s = acc * inv_h;
    }
    float mx = blockMax(s, red, t);
    float e = (t < A) ? __expf(s - mx) : 0.f;
    float tot = blockSum(e, red, t);
    sa[t] = e / tot;
    __syncthreads();
    float u0 = 0.f, u1 = 0.f;
    for (int a = 0; a < A; ++a) {
        float w = sa[a];
        const float* row = nr + ((size_t)b * NPU + a) * RR;
        u0 += w * row[t];
        u1 += w * row[t + 256];
    }
    uL[t] = u0; uL[t + 256] = u1;
    __syncthreads();
#pragma unroll 1
    for (int k = 0; k < 4; ++k) {
        int i = t + k * 256;
        const float4* w4 = (const float4*)(out_w + (size_t)i * RR);
        float acc = 0.f;
        for (int kc = 0; kc < 128; ++kc) acc += dot4(w4[kc], ((const float4*)uL)[kc]);
        npuL[i] = acc + out_b[i];
    }
    __syncthreads();
    float ag[8];
#pragma unroll 1
    for (int k = 0; k < 8; ++k) {
        int h = t + k * 256;
        const float4* w4 = (const float4*)(proj_w + (size_t)h * INP);
        float acc = 0.f;
        for (int kc = 0; kc < 256; ++kc) acc += dot4(w4[kc], ((const float4*)npuL)[kc]);
        ag[k] = acc + proj_b[h];
        aggS[h] = ag[k];
    }
    (void)aggS;
    float ms = 0.f;
#pragma unroll
    for (int k = 0; k < 8; ++k) ms += ag[k];
    float mu = blockSum(ms, red, t) * (1.f / HIDN);
    float vs = 0.f;
#pragma unroll
    for (int k = 0; k < 8; ++k) { float d = ag[k] - mu; vs += d * d; }
    float var = blockSum(vs, red, t) * (1.f / HIDN);
    float rs = rsqrtf(var + 1e-5f);
#pragma unroll
    for (int k = 0; k < 8; ++k) {
        int h = t + k * 256;
        out[(size_t)b * HIDN + h] = (ag[k] - mu) * rs * ln_g[h] + ln_b[h];
    }
}

extern "C" void kernel_launch(void* const* d_in, const int* in_sizes, int n_in,
                              void* d_out, int out_size, void* d_ws, size_t ws_size,
                              hipStream_t stream) {
    (void)in_sizes; (void)n_in; (void)out_size; (void)ws_size;
    const float* x      = (const float*)d_in[0];
    const float* hidden = (const float*)d_in[1];
    const float* mem    = (const float*)d_in[2];
    const float* mmu_w  = (const float*)d_in[3];
    const float* mmu_b  = (const float*)d_in[4];
    const float* w_ih   = (const float*)d_in[5];
    const float* b_ih   = (const float*)d_in[6];
    const float* w_hh   = (const float*)d_in[7];
    const float* b_hh   = (const float*)d_in[8];
    const float* out_w  = (const float*)d_in[9];
    const float* out_b  = (const float*)d_in[10];
    const float* agg_q  = (const float*)d_in[11];
    const float* proj_w = (const float*)d_in[12];
    const float* proj_b = (const float*)d_in[13];
    const float* ln_g   = (const float*)d_in[14];
    const float* ln_b   = (const float*)d_in[15];
    const int*   anp    = (const int*)d_in[16];

    float* ws = (float*)d_ws;
    float* query = ws + OFF_QUERY;
    float* wkey  = ws + OFF_WKEY;
    float* wval  = ws + OFF_WVAL;
    float* rdata = ws + OFF_RDATA;
    float* wgate = ws + OFF_WGATE;
    float* wmaxp = ws + OFF_WMAX;
    float* wsump = ws + OFF_WSUM;
    float* gix   = ws + OFF_GIX;
    float* pvec  = ws + OFF_P;
    float* rvec  = ws + OFF_R;
    __hip_bfloat16* swsc = (__hip_bfloat16*)((char*)d_ws + OFF_FEND * 4);

    float* outv = (float*)d_out;
    float* outh = outv + (size_t)BB * HIDN;
    float* outm = outh + (size_t)BB * NPU * RR;

    kP0<<<4, 256, 0, stream>>>(proj_w, agg_q, pvec);
    kP1<<<2, 256, 0, stream>>>(out_w, pvec, rvec);
    kCopyHidden<<<2048, 256, 0, stream>>>((const float4*)hidden, (float4*)outh);
    kGix<<<dim3(BB, 6), 256, 0, stream>>>(x, w_ih, b_ih, gix);
    kMmu<<<dim3(BB, 16), 256, 0, stream>>>(hidden, mmu_w, mmu_b, query, wkey, wval, wgate, anp);
    kAttnMfma<<<dim3(NPU / 64, BB), 512, 0, stream>>>(mem, query, wkey, rdata,
                                                      (unsigned short*)swsc, wmaxp, wsump, anp);
    kGru<<<dim3(BB, 16), 256, 0, stream>>>(hidden, rdata, w_ih, w_hh, b_hh, gix, outh, anp);
    kWrite<<<dim3(BB, MEMN / MT), 256, 0, stream>>>(mem, wval, wgate, wmaxp, wsump, swsc, outm, anp);
    kOut<<<BB, 256, 0, stream>>>(outh, rvec, out_w, out_b, proj_w, proj_b, ln_g, ln_b, outv, anp);
}

// Round 2
// 6144.169 us; speedup vs baseline: 1.5473x; 1.5473x over previous
//
#include <hip/hip_runtime.h>
#include <hip/hip_bf16.h>
#include <math.h>

#define BB   64
#define INP  1024
#define HIDN 2048
#define NPU  256
#define MEMN 4096
#define RR   512
#define DD   512
#define MMU_USED 1537   // 3*D + 1 gate col; remaining 1027 rows of mmu_w are unused by reference

// ---- workspace layout (float units; bf16 block at end) ----
#define OFF_QUERY  ((size_t)0)
#define OFF_WKEY   (OFF_QUERY + (size_t)BB*NPU*DD)
#define OFF_WVAL   (OFF_WKEY  + (size_t)BB*NPU*DD)   // now bf16 wvalT [b][d][a] (uses half the slot)
#define OFF_RDATA  (OFF_WVAL  + (size_t)BB*NPU*DD)
#define OFF_WGATE  (OFF_RDATA + (size_t)BB*NPU*DD)
#define OFF_WMAX   (OFF_WGATE + (size_t)BB*NPU)
#define OFF_WSUM   (OFF_WMAX  + (size_t)BB*NPU)
#define OFF_GIX    (OFF_WSUM  + (size_t)BB*NPU)
#define OFF_P      (OFF_GIX   + (size_t)BB*1536)
#define OFF_R      (OFF_P     + 1024)
#define OFF_FEND   (OFF_R     + 512)
// swsc (bf16 write scores, B*NPU*MEMN elems) at byte offset OFF_FEND*4

typedef __bf16 bf16_t;
typedef bf16_t bf16x8 __attribute__((ext_vector_type(8)));
typedef unsigned short u16x8 __attribute__((ext_vector_type(8)));
typedef unsigned short u16x4 __attribute__((ext_vector_type(4)));
typedef float f32x4 __attribute__((ext_vector_type(4)));

__device__ __forceinline__ unsigned short f2bf(float f) {
    unsigned u = __builtin_bit_cast(unsigned, f);
    unsigned r = u + 0x7FFFu + ((u >> 16) & 1u);   // RNE, matches __float2bfloat16
    return (unsigned short)(r >> 16);
}
__device__ __forceinline__ float bf2f(unsigned short u) {
    return __builtin_bit_cast(float, (unsigned)u << 16);
}

__device__ __forceinline__ float dot4(float4 a, float4 b) {
    return a.x*b.x + a.y*b.y + a.z*b.z + a.w*b.w;
}

// p[i] = sum_h agg_q[h] * proj_w[h,i]
__global__ __launch_bounds__(256) void kP0(const float* __restrict__ proj_w,
                                           const float* __restrict__ agg_q,
                                           float* __restrict__ p) {
    int i = blockIdx.x * 256 + threadIdx.x;      // < 1024
    float acc = 0.f;
    for (int h = 0; h < HIDN; ++h) acc += agg_q[h] * proj_w[(size_t)h * INP + i];
    p[i] = acc;
}

// r[j] = sum_i p[i] * out_w[i,j]
__global__ __launch_bounds__(256) void kP1(const float* __restrict__ out_w,
                                           const float* __restrict__ p,
                                           float* __restrict__ r) {
    int j = blockIdx.x * 256 + threadIdx.x;      // < 512
    float acc = 0.f;
    for (int i = 0; i < INP; ++i) acc += p[i] * out_w[(size_t)i * RR + j];
    r[j] = acc;
}

// pass-through copy hidden_state -> out hidden region (rows >= A keep original)
__global__ __launch_bounds__(256) void kCopyHidden(const float4* __restrict__ src,
                                                   float4* __restrict__ dst) {
    int idx = blockIdx.x * 256 + threadIdx.x;    // grid 2048 -> 524288 threads
#pragma unroll
    for (int j = 0; j < 4; ++j) dst[idx + j * 524288] = src[idx + j * 524288];
}

// gix[b,n] = b_ih[n] + sum_{i<1024} x[b,i]*W_ih[n,i]   (x part of GRU input GEMM, per-b only)
__global__ __launch_bounds__(256) void kGix(const float* __restrict__ x,
                                            const float* __restrict__ w_ih,
                                            const float* __restrict__ b_ih,
                                            float* __restrict__ gix) {
    int b = blockIdx.x;
    int n = blockIdx.y * 256 + threadIdx.x;      // < 1536
    __shared__ __align__(16) float xs[INP];
    for (int i = threadIdx.x; i < INP; i += 256) xs[i] = x[(size_t)b * INP + i];
    __syncthreads();
    const float4* w  = (const float4*)(w_ih + (size_t)n * 1536);
    const float4* xv = (const float4*)xs;
    float acc = 0.f;
    for (int kc = 0; kc < 256; ++kc) acc += dot4(w[kc], xv[kc]);
    gix[(size_t)b * 1536 + n] = acc + b_ih[n];
}

// mmu GEMM: (16 NPUs per block) x 1537 used output rows.
// w_val output goes out TRANSPOSED in bf16: wvalT[b][d][a] (MFMA A-operand layout for kWriteMfma).
__global__ __launch_bounds__(256) void kMmu(const float* __restrict__ hidden,
                                            const float* __restrict__ mmu_w,
                                            const float* __restrict__ mmu_b,
                                            float* __restrict__ query, float* __restrict__ wkey,
                                            unsigned short* __restrict__ wvalT, float* __restrict__ wgate,
                                            const int* __restrict__ anp) {
    int b = blockIdx.x, at = blockIdx.y, t = threadIdx.x;
    int A = *anp;
    int a0 = at * 16;
    __shared__ __align__(16) float regs[16 * RR];
    const float4* src = (const float4*)(hidden + ((size_t)b * NPU + a0) * RR);
#pragma unroll
    for (int j = 0; j < 8; ++j) ((float4*)regs)[t + j * 256] = src[t + j * 256];
    __syncthreads();
    for (int n = t; n < MMU_USED; n += 256) {
        const float4* w = (const float4*)(mmu_w + (size_t)n * RR);
        float acc[16];
#pragma unroll
        for (int a = 0; a < 16; ++a) acc[a] = 0.f;
        for (int kc = 0; kc < 128; ++kc) {
            float4 wv = w[kc];
#pragma unroll
            for (int a = 0; a < 16; ++a)
                acc[a] += dot4(wv, ((const float4*)regs)[a * 128 + kc]);  // LDS broadcast
        }
        float bias = mmu_b[n];
#pragma unroll
        for (int a = 0; a < 16; ++a) {
            int aa = a0 + a;
            if (aa >= A) continue;
            float v = acc[a] + bias;
            size_t base = (size_t)b * NPU + aa;
            if (n < 512)       query[base * DD + n] = v;
            else if (n < 1024) wkey [base * DD + n - 512] = v;
            else if (n < 1536) wvalT[((size_t)b * DD + (n - 1024)) * NPU + aa] = f2bf(v);
            else               wgate[base] = 1.f / (1.f + __expf(-v));
        }
    }
}

// ============================================================================
// MFMA flash attention (read scores + write-score stats), bf16 matrix cores.
// ============================================================================

#define LDSOFF_MROW 0        // 64 rows x 1024B  (bf16 [m][d]), swz ^((m&7)<<4)
#define LDSOFF_MT   65536    // 512 rows x 128B  (bf16 [d][m]), swz ^((((d>>3)^d)&7)<<4)
#define LDSOFF_P    131072   // 64 rows x 128B   (bf16 [a][m]), swz ^((a&7)<<4)
#define LDSOFF_SCL  139264   // 64 f32 rescale factors
#define LDSOFF_LFIN 139520   // 64 f32 final softmax denominators
#define LDSOFF_FLG  139776   // 4 ints rescale-needed flags
#define LDS_TOTAL   139808

#define BARRIER_LDS() do { \
    asm volatile("s_waitcnt lgkmcnt(0)" ::: "memory"); \
    __builtin_amdgcn_sched_barrier(0); \
    __builtin_amdgcn_s_barrier(); \
    asm volatile("" ::: "memory"); \
    __builtin_amdgcn_sched_barrier(0); \
} while (0)

__global__ __launch_bounds__(512, 2) void kAttnMfma(
    const float* __restrict__ mem,
    const float* __restrict__ query,
    const float* __restrict__ wkey,
    float* __restrict__ rdata,
    unsigned short* __restrict__ swsc,
    float* __restrict__ wmax, float* __restrict__ wsum,
    const int* __restrict__ anp)
{
    __shared__ __align__(16) char smem[LDS_TOTAL];
    const int A   = *anp;
    const int b   = blockIdx.y;
    const int Ab0 = blockIdx.x * 64;
    if (Ab0 >= A) return;

    const int t    = threadIdx.x;
    const int wv   = t >> 6;         // wave 0..7
    const int lane = t & 63;
    const int r    = lane & 15;      // MFMA row/col lane index
    const int g    = lane >> 4;      // MFMA k-group
    const bool isS = (wv < 4);
    const int aBase = (isS ? wv : wv - 4) << 4;   // wave's 16-NPU slice (rel.)
    const float inv = 0.044194173824159216f;      // 1/sqrt(512)

    const float* mrow_base = mem + (size_t)b * MEMN * DD;

    // ---- issue staging loads for tile 0 (rows 8*wv+i, cols 8*lane..) ----
    float4 stg[16];
    {
        const float4* sp = (const float4*)(mrow_base + (size_t)(8 * wv) * DD) + lane * 2;
#pragma unroll
        for (int i = 0; i < 8; ++i) { stg[2*i] = sp[i*128]; stg[2*i+1] = sp[i*128+1]; }
    }

    // ---- Q/K fragments, scaled by inv, held in registers (64 VGPR) ----
    bf16x8 qf[16];
    {
        const int aG = Ab0 + aBase + r;
        const bool act = (aG < A);
        const float* qsrc = (isS ? query : wkey) + ((size_t)b * NPU + aG) * DD + 8 * g;
#pragma unroll
        for (int kk = 0; kk < 16; ++kk) {
            float4 v0 = make_float4(0.f,0.f,0.f,0.f), v1 = make_float4(0.f,0.f,0.f,0.f);
            if (act) {
                const float4* p4 = (const float4*)(qsrc + kk * 32);
                v0 = p4[0]; v1 = p4[1];
            }
            u16x8 uv = { f2bf(v0.x*inv), f2bf(v0.y*inv), f2bf(v0.z*inv), f2bf(v0.w*inv),
                         f2bf(v1.x*inv), f2bf(v1.y*inv), f2bf(v1.z*inv), f2bf(v1.w*inv) };
            qf[kk] = __builtin_bit_cast(bf16x8, uv);
        }
    }

    float* scl_lds  = (float*)(smem + LDSOFF_SCL);
    float* lfin_lds = (float*)(smem + LDSOFF_LFIN);
    int*   flg_lds  = (int*)(smem + LDSOFF_FLG);

    f32x4 pacc[4][4];
    {
        f32x4 z = {0.f, 0.f, 0.f, 0.f};
#pragma unroll
        for (int i = 0; i < 4; ++i)
#pragma unroll
            for (int j = 0; j < 4; ++j) pacc[i][j] = z;
    }
    float mrun = -INFINITY, lrun = 0.f;

    for (int tt = 0; tt < MEMN / 64; ++tt) {
        const int m0 = tt * 64;

        // ===== stage: cvt + dual-layout LDS write (tile tt) =====
        unsigned short bv[8][8];
#pragma unroll
        for (int i = 0; i < 8; ++i) {
            float4 lo = stg[2*i], hi = stg[2*i+1];
            bv[i][0]=f2bf(lo.x); bv[i][1]=f2bf(lo.y); bv[i][2]=f2bf(lo.z); bv[i][3]=f2bf(lo.w);
            bv[i][4]=f2bf(hi.x); bv[i][5]=f2bf(hi.y); bv[i][6]=f2bf(hi.z); bv[i][7]=f2bf(hi.w);
            int m = 8 * wv + i;
            int byte = (m << 10) + (lane << 4);
            byte ^= (m & 7) << 4;
            u16x8 rv = { bv[i][0],bv[i][1],bv[i][2],bv[i][3],bv[i][4],bv[i][5],bv[i][6],bv[i][7] };
            *(u16x8*)(smem + LDSOFF_MROW + byte) = rv;
        }
#pragma unroll
        for (int j = 0; j < 8; ++j) {
            int d = 8 * lane + j;
            int byte = (d << 7) + (wv << 4);
            byte ^= (((d >> 3) ^ d) & 7) << 4;
            u16x8 cv = { bv[0][j],bv[1][j],bv[2][j],bv[3][j],bv[4][j],bv[5][j],bv[6][j],bv[7][j] };
            *(u16x8*)(smem + LDSOFF_MT + byte) = cv;
        }
        if (tt + 1 < MEMN / 64) {
            const float4* sp = (const float4*)(mrow_base + (size_t)((tt+1)*64 + 8*wv) * DD) + lane * 2;
#pragma unroll
            for (int i = 0; i < 8; ++i) { stg[2*i] = sp[i*128]; stg[2*i+1] = sp[i*128+1]; }
        }
        BARRIER_LDS();

        // ===== phase B: scores S^T (or Sw^T), 64m x 16a per wave =====
        f32x4 sacc[4];
        {
            f32x4 z = {0.f, 0.f, 0.f, 0.f};
            sacc[0] = z; sacc[1] = z; sacc[2] = z; sacc[3] = z;
        }
#pragma unroll
        for (int kk = 0; kk < 16; ++kk) {
#pragma unroll
            for (int ms = 0; ms < 4; ++ms) {
                int m = ms * 16 + r;
                int byte = (m << 10) + (kk << 6) + (g << 4);
                byte ^= (m & 7) << 4;
                bf16x8 af = *(const bf16x8*)(smem + LDSOFF_MROW + byte);
                sacc[ms] = __builtin_amdgcn_mfma_f32_16x16x32_bf16(af, qf[kk], sacc[ms], 0, 0, 0);
            }
        }
        float tmax = -INFINITY;
#pragma unroll
        for (int ms = 0; ms < 4; ++ms)
            tmax = fmaxf(tmax, fmaxf(fmaxf(sacc[ms][0], sacc[ms][1]),
                                     fmaxf(sacc[ms][2], sacc[ms][3])));
        tmax = fmaxf(tmax, __shfl_xor(tmax, 16));
        tmax = fmaxf(tmax, __shfl_xor(tmax, 32));
        float mnew = fmaxf(mrun, tmax);
        float sclf = __expf(mrun - mnew);
        float lsum = 0.f;
        if (isS) {
            int aRel = aBase + r;
#pragma unroll
            for (int ms = 0; ms < 4; ++ms) {
                float p0 = __expf(sacc[ms][0] - mnew), p1 = __expf(sacc[ms][1] - mnew);
                float p2 = __expf(sacc[ms][2] - mnew), p3 = __expf(sacc[ms][3] - mnew);
                lsum += (p0 + p1) + (p2 + p3);
                u16x4 pk = { f2bf(p0), f2bf(p1), f2bf(p2), f2bf(p3) };
                int byte = (aRel << 7) + (ms << 5) + (g << 3);
                byte ^= (r & 7) << 4;
                *(u16x4*)(smem + LDSOFF_P + byte) = pk;
            }
            if (lane < 16) scl_lds[aBase + lane] = sclf;
            int fneed = __any(sclf != 1.f);
            if (lane == 0) flg_lds[wv] = fneed;
        } else {
            int aG = Ab0 + aBase + r;
#pragma unroll
            for (int ms = 0; ms < 4; ++ms) {
                lsum += (__expf(sacc[ms][0] - mnew) + __expf(sacc[ms][1] - mnew))
                      + (__expf(sacc[ms][2] - mnew) + __expf(sacc[ms][3] - mnew));
            }
            if (aG < A) {
                size_t sb = ((size_t)b * NPU + aG) * MEMN + m0 + 4 * g;
#pragma unroll
                for (int ms = 0; ms < 4; ++ms) {
                    u16x4 sv = { f2bf(sacc[ms][0]), f2bf(sacc[ms][1]),
                                 f2bf(sacc[ms][2]), f2bf(sacc[ms][3]) };
                    *(u16x4*)(swsc + sb + ms * 16) = sv;
                }
            }
        }
        lsum += __shfl_xor(lsum, 16);
        lsum += __shfl_xor(lsum, 32);
        lrun = lrun * sclf + lsum;
        mrun = mnew;
        BARRIER_LDS();

        // ===== phase C: PV accumulate (all 8 waves, d-slice 64 each) =====
        int f = flg_lds[0] | flg_lds[1] | flg_lds[2] | flg_lds[3];
        if (f) {
#pragma unroll
            for (int as = 0; as < 4; ++as)
#pragma unroll
                for (int rg = 0; rg < 4; ++rg) {
                    float sc = scl_lds[as * 16 + 4 * g + rg];
#pragma unroll
                    for (int ds = 0; ds < 4; ++ds) pacc[as][ds][rg] *= sc;
                }
        }
#pragma unroll
        for (int as = 0; as < 4; ++as) {
            int ar = as * 16 + r;
            int ab0 = ((ar << 7) + (g << 4)) ^ ((r & 7) << 4);
            int ab1 = ((ar << 7) + 64 + (g << 4)) ^ ((r & 7) << 4);
            bf16x8 pa0 = *(const bf16x8*)(smem + LDSOFF_P + ab0);
            bf16x8 pa1 = *(const bf16x8*)(smem + LDSOFF_P + ab1);
#pragma unroll
            for (int ds = 0; ds < 4; ++ds) {
                int d = (wv << 6) + (ds << 4) + r;
                int key = (((d >> 3) ^ d) & 7) << 4;
                int mb0 = ((d << 7) + (g << 4)) ^ key;
                int mb1 = ((d << 7) + 64 + (g << 4)) ^ key;
                bf16x8 bm0 = *(const bf16x8*)(smem + LDSOFF_MT + mb0);
                bf16x8 bm1 = *(const bf16x8*)(smem + LDSOFF_MT + mb1);
                pacc[as][ds] = __builtin_amdgcn_mfma_f32_16x16x32_bf16(pa0, bm0, pacc[as][ds], 0, 0, 0);
                pacc[as][ds] = __builtin_amdgcn_mfma_f32_16x16x32_bf16(pa1, bm1, pacc[as][ds], 0, 0, 0);
            }
        }
        BARRIER_LDS();
    }

    // ===== epilogue =====
    if (isS) {
        if (lane < 16) lfin_lds[aBase + lane] = lrun;
    } else if (lane < 16) {
        int aG = Ab0 + aBase + lane;
        if (aG < A) {
            wmax[(size_t)b * NPU + aG] = mrun;
            wsum[(size_t)b * NPU + aG] = lrun;
        }
    }
    BARRIER_LDS();
#pragma unroll
    for (int as = 0; as < 4; ++as)
#pragma unroll
        for (int rg = 0; rg < 4; ++rg) {
            int aRel = as * 16 + 4 * g + rg;
            int aG = Ab0 + aRel;
            if (aG < A) {
                float invl = 1.f / lfin_lds[aRel];
#pragma unroll
                for (int ds = 0; ds < 4; ++ds) {
                    int d = (wv << 6) + (ds << 4) + r;
                    rdata[((size_t)b * NPU + aG) * DD + d] = pacc[as][ds][rg] * invl;
                }
            }
        }
}

// GRU cell, 16 a's per block, thread owns j and j+256
__global__ __launch_bounds__(256) void kGru(const float* __restrict__ hidden,
                                            const float* __restrict__ rdata,
                                            const float* __restrict__ w_ih,
                                            const float* __restrict__ w_hh,
                                            const float* __restrict__ b_hh,
                                            const float* __restrict__ gix,
                                            float* __restrict__ out_hidden,
                                            const int* __restrict__ anp) {
    int b = blockIdx.x, at = blockIdx.y, t = threadIdx.x;
    int A = *anp;
    int a0 = at * 16;
    __shared__ __align__(16) float rd[16 * RR];
    __shared__ __align__(16) float hh[16 * RR];
    const float4* s1 = (const float4*)(rdata  + ((size_t)b * NPU + a0) * DD);
    const float4* s2 = (const float4*)(hidden + ((size_t)b * NPU + a0) * RR);
#pragma unroll
    for (int j = 0; j < 8; ++j) {
        ((float4*)rd)[t + j * 256] = s1[t + j * 256];
        ((float4*)hh)[t + j * 256] = s2[t + j * 256];
    }
    __syncthreads();
#pragma unroll 1
    for (int jj = 0; jj < 2; ++jj) {
        int j = t + jj * 256;
        float rv[16], zv[16];
#pragma unroll 1
        for (int gate = 0; gate < 3; ++gate) {
            int n = gate * RR + j;
            const float4* wi = (const float4*)(w_ih + (size_t)n * 1536 + 1024);
            const float4* wh = (const float4*)(w_hh + (size_t)n * RR);
            float ai[16], ah[16];
#pragma unroll
            for (int a = 0; a < 16; ++a) { ai[a] = 0.f; ah[a] = 0.f; }
            for (int kc = 0; kc < 128; ++kc) {
                float4 wiv = wi[kc];
                float4 whv = wh[kc];
#pragma unroll
                for (int a = 0; a < 16; ++a) {
                    ai[a] += dot4(wiv, ((const float4*)rd)[a * 128 + kc]);
                    ah[a] += dot4(whv, ((const float4*)hh)[a * 128 + kc]);
                }
            }
            float gx = gix[(size_t)b * 1536 + n];
            float bh = b_hh[n];
            if (gate == 0) {
#pragma unroll
                for (int a = 0; a < 16; ++a) rv[a] = 1.f / (1.f + __expf(-(ai[a] + gx + ah[a] + bh)));
            } else if (gate == 1) {
#pragma unroll
                for (int a = 0; a < 16; ++a) zv[a] = 1.f / (1.f + __expf(-(ai[a] + gx + ah[a] + bh)));
            } else {
#pragma unroll
                for (int a = 0; a < 16; ++a) {
                    int aa = a0 + a;
                    if (aa >= A) continue;
                    float nn = tanhf(ai[a] + gx + rv[a] * (ah[a] + bh));
                    float h = hh[a * RR + j];
                    out_hidden[((size_t)b * NPU + aa) * RR + j] = (1.f - zv[a]) * nn + zv[a] * h;
                }
            }
        }
    }
}

// ============================================================================
// MFMA memory-write: new_mem[m][d] = mem[m][d]*(1-tw[m]) + sum_a contrib[m][a]*wval[a][d]
// D^T form: D[d][m] = A(wvalT[d][a]) x B(contrib[m][a]) so lane's 4 acc regs are
// 4 consecutive d -> one float4 store. 64-m tile, K=256 (a), 512 thr = 8 waves,
// wave owns a 64-wide d-slice. contrib staged bf16 in XOR-swizzled LDS.
// ============================================================================
__global__ __launch_bounds__(512) void kWriteMfma(
    const float* __restrict__ mem,
    const unsigned short* __restrict__ wvalT,   // bf16 [b][d=512][a=256]
    const float* __restrict__ wgate,
    const float* __restrict__ wmax,
    const float* __restrict__ wsum,
    const unsigned short* __restrict__ swsc,    // bf16 [b][a][m=4096]
    float* __restrict__ out_mem,
    const int* __restrict__ anp)
{
    const int A  = *anp;
    const int b  = blockIdx.y;
    const int m0 = blockIdx.x * 64;
    const int t  = threadIdx.x;
    const int wv = t >> 6, lane = t & 63;
    const int r  = lane & 15, g = lane >> 4;

    __shared__ __align__(16) char contribL[64 * 512];   // bf16 [m][a], pitch 512B, swz ^((m&7)<<4)
    __shared__ float ec[NPU], wm[NPU];
    __shared__ float twp[8][64];
    __shared__ float twL[64];

    if (t < NPU) {
        float e = 0.f, w = 0.f;
        if (t < A) {
            e = wgate[(size_t)b * NPU + t] / wsum[(size_t)b * NPU + t];
            w = wmax[(size_t)b * NPU + t];
        }
        ec[t] = e; wm[t] = w;
    }
    __syncthreads();

    // contrib fill: 32 values/thread; coalesced 128B swsc reads per 64-thread group
#pragma unroll
    for (int i = 0; i < 32; ++i) {
        int flat = t + i * 512;
        int a = flat >> 6, m = flat & 63;
        float c = 0.f;
        if (a < A) {
            unsigned short s = swsc[((size_t)b * NPU + a) * MEMN + m0 + m];
            c = ec[a] * __expf(bf2f(s) - wm[a]);
        }
        int byte = (m * 512 + a * 2) ^ ((m & 7) << 4);
        *(unsigned short*)(contribL + byte) = f2bf(c);
    }
    __syncthreads();

    // total_weight[m] = clamp(sum_a contrib, 0, 1) -- from the SAME bf16 operand
    {
        int m = t & 63, c8 = t >> 6;
        float s = 0.f;
#pragma unroll
        for (int i = 0; i < 32; ++i) {
            int a = c8 * 32 + i;
            int byte = (m * 512 + a * 2) ^ ((m & 7) << 4);
            s += bf2f(*(const unsigned short*)(contribL + byte));
        }
        twp[c8][m] = s;
    }
    __syncthreads();
    if (t < 64) {
        float s = 0.f;
#pragma unroll
        for (int c8 = 0; c8 < 8; ++c8) s += twp[c8][t];
        twL[t] = fminf(fmaxf(s, 0.f), 1.f);
    }

    // GEMM: per wave D[d-slice 64][m 64], K = 256 in 8 steps of 32
    f32x4 acc[4][4];   // [ds][ms]
    {
        f32x4 z = {0.f, 0.f, 0.f, 0.f};
#pragma unroll
        for (int i = 0; i < 4; ++i)
#pragma unroll
            for (int j = 0; j < 4; ++j) acc[i][j] = z;
    }
    const unsigned short* wvb = wvalT + (size_t)b * DD * NPU;
#pragma unroll 1
    for (int kk = 0; kk < 8; ++kk) {
        bf16x8 af[4];
#pragma unroll
        for (int ds = 0; ds < 4; ++ds) {
            int d = (wv << 6) + ds * 16 + r;
            af[ds] = *(const bf16x8*)(wvb + (size_t)d * NPU + kk * 32 + g * 8);
        }
        bf16x8 bfr[4];
#pragma unroll
        for (int ms = 0; ms < 4; ++ms) {
            int m = ms * 16 + r;
            int byte = (m * 512 + kk * 64 + g * 16) ^ ((m & 7) << 4);
            bfr[ms] = *(const bf16x8*)(contribL + byte);
        }
#pragma unroll
        for (int ds = 0; ds < 4; ++ds)
#pragma unroll
            for (int ms = 0; ms < 4; ++ms)
                acc[ds][ms] = __builtin_amdgcn_mfma_f32_16x16x32_bf16(af[ds], bfr[ms], acc[ds][ms], 0, 0, 0);
    }
    __syncthreads();   // twL ready for all

    // epilogue: lane holds col m = ms*16+r, rows d = wv*64 + ds*16 + g*4 + (0..3)
#pragma unroll
    for (int ds = 0; ds < 4; ++ds)
#pragma unroll
        for (int ms = 0; ms < 4; ++ms) {
            int m = m0 + ms * 16 + r;
            int d = (wv << 6) + ds * 16 + (g << 2);
            size_t off = ((size_t)b * MEMN + m) * DD + d;
            float4 mv = *(const float4*)(mem + off);
            float tw = twL[ms * 16 + r];
            float s1 = 1.f - tw;
            float4 res = make_float4(mv.x * s1 + acc[ds][ms][0],
                                     mv.y * s1 + acc[ds][ms][1],
                                     mv.z * s1 + acc[ds][ms][2],
                                     mv.w * s1 + acc[ds][ms][3]);
            *(float4*)(out_mem + off) = res;
        }
}

__device__ __forceinline__ float blockSum(float v, float* red, int t) {
#pragma unroll
    for (int off = 32; off >= 1; off >>= 1) v += __shfl_xor(v, off);
    __syncthreads();
    if ((t & 63) == 0) red[t >> 6] = v;
    __syncthreads();
    return red[0] + red[1] + red[2] + red[3];
}
__device__ __forceinline__ float blockMax(float v, float* red, int t) {
#pragma unroll
    for (int off = 32; off >= 1; off >>= 1) v = fmaxf(v, __shfl_xor(v, off));
    __syncthreads();
    if ((t & 63) == 0) red[t >> 6] = v;
    __syncthreads();
    return fmaxf(fmaxf(red[0], red[1]), fmaxf(red[2], red[3]));
}

// collapsed output head: softmax over a of r.new_regs, then proj(out(u)), then LN
__global__ __launch_bounds__(256) void kOut(const float* __restrict__ nr,
                                            const float* __restrict__ rvec,
                                            const float* __restrict__ out_w,
                                            const float* __restrict__ out_b,
                                            const float* __restrict__ proj_w,
                                            const float* __restrict__ proj_b,
                                            const float* __restrict__ ln_g,
                                            const float* __restrict__ ln_b,
                                            float* __restrict__ out,
                                            const int* __restrict__ anp) {
    int b = blockIdx.x, t = threadIdx.x;
    int A = *anp;
    __shared__ float sa[NPU];
    __shared__ __align__(16) float uL[RR];
    __shared__ __align__(16) float npuL[INP];
    __shared__ float red[4];
    const float inv_h = 0.022097086912079608f;  // 1/sqrt(2048)
    float s = -INFINITY;
    if (t < A) {
        const float4* row = (const float4*)(nr + ((size_t)b * NPU + t) * RR);
        const float4* rv4 = (const float4*)rvec;
        float acc = 0.f;
        for (int i = 0; i < 128; ++i) acc += dot4(row[i], rv4[i]);
        s = acc * inv_h;
    }
    float mx = blockMax(s, red, t);
    float e = (t < A) ? __expf(s - mx) : 0.f;
    float tot = blockSum(e, red, t);
    sa[t] = e / tot;
    __syncthreads();
    float u0 = 0.f, u1 = 0.f;
    for (int a = 0; a < A; ++a) {
        float w = sa[a];
        const float* row = nr + ((size_t)b * NPU + a) * RR;
        u0 += w * row[t];
        u1 += w * row[t + 256];
    }
    uL[t] = u0; uL[t + 256] = u1;
    __syncthreads();
#pragma unroll 1
    for (int k = 0; k < 4; ++k) {
        int i = t + k * 256;
        const float4* w4 = (const float4*)(out_w + (size_t)i * RR);
        float acc = 0.f;
        for (int kc = 0; kc < 128; ++kc) acc += dot4(w4[kc], ((const float4*)uL)[kc]);
        npuL[i] = acc + out_b[i];
    }
    __syncthreads();
    float ag[8];
#pragma unroll 1
    for (int k = 0; k < 8; ++k) {
        int h = t + k * 256;
        const float4* w4 = (const float4*)(proj_w + (size_t)h * INP);
        float acc = 0.f;
        for (int kc = 0; kc < 256; ++kc) acc += dot4(w4[kc], ((const float4*)npuL)[kc]);
        ag[k] = acc + proj_b[h];
    }
    float ms = 0.f;
#pragma unroll
    for (int k = 0; k < 8; ++k) ms += ag[k];
    float mu = blockSum(ms, red, t) * (1.f / HIDN);
    float vs = 0.f;
#pragma unroll
    for (int k = 0; k < 8; ++k) { float d = ag[k] - mu; vs += d * d; }
    float var = blockSum(vs, red, t) * (1.f / HIDN);
    float rs = rsqrtf(var + 1e-5f);
#pragma unroll
    for (int k = 0; k < 8; ++k) {
        int h = t + k * 256;
        out[(size_t)b * HIDN + h] = (ag[k] - mu) * rs * ln_g[h] + ln_b[h];
    }
}

extern "C" void kernel_launch(void* const* d_in, const int* in_sizes, int n_in,
                              void* d_out, int out_size, void* d_ws, size_t ws_size,
                              hipStream_t stream) {
    (void)in_sizes; (void)n_in; (void)out_size; (void)ws_size;
    const float* x      = (const float*)d_in[0];
    const float* hidden = (const float*)d_in[1];
    const float* mem    = (const float*)d_in[2];
    const float* mmu_w  = (const float*)d_in[3];
    const float* mmu_b  = (const float*)d_in[4];
    const float* w_ih   = (const float*)d_in[5];
    const float* b_ih   = (const float*)d_in[6];
    const float* w_hh   = (const float*)d_in[7];
    const float* b_hh   = (const float*)d_in[8];
    const float* out_w  = (const float*)d_in[9];
    const float* out_b  = (const float*)d_in[10];
    const float* agg_q  = (const float*)d_in[11];
    const float* proj_w = (const float*)d_in[12];
    const float* proj_b = (const float*)d_in[13];
    const float* ln_g   = (const float*)d_in[14];
    const float* ln_b   = (const float*)d_in[15];
    const int*   anp    = (const int*)d_in[16];

    float* ws = (float*)d_ws;
    float* query = ws + OFF_QUERY;
    float* wkey  = ws + OFF_WKEY;
    unsigned short* wvalT = (unsigned short*)(ws + OFF_WVAL);
    float* rdata = ws + OFF_RDATA;
    float* wgate = ws + OFF_WGATE;
    float* wmaxp = ws + OFF_WMAX;
    float* wsump = ws + OFF_WSUM;
    float* gix   = ws + OFF_GIX;
    float* pvec  = ws + OFF_P;
    float* rvec  = ws + OFF_R;
    unsigned short* swsc = (unsigned short*)((char*)d_ws + OFF_FEND * 4);

    float* outv = (float*)d_out;
    float* outh = outv + (size_t)BB * HIDN;
    float* outm = outh + (size_t)BB * NPU * RR;

    kP0<<<4, 256, 0, stream>>>(proj_w, agg_q, pvec);
    kP1<<<2, 256, 0, stream>>>(out_w, pvec, rvec);
    kCopyHidden<<<2048, 256, 0, stream>>>((const float4*)hidden, (float4*)outh);
    kGix<<<dim3(BB, 6), 256, 0, stream>>>(x, w_ih, b_ih, gix);
    kMmu<<<dim3(BB, 16), 256, 0, stream>>>(hidden, mmu_w, mmu_b, query, wkey, wvalT, wgate, anp);
    kAttnMfma<<<dim3(NPU / 64, BB), 512, 0, stream>>>(mem, query, wkey, rdata,
                                                      swsc, wmaxp, wsump, anp);
    kGru<<<dim3(BB, 16), 256, 0, stream>>>(hidden, rdata, w_ih, w_hh, b_hh, gix, outh, anp);
    kWriteMfma<<<dim3(MEMN / 64, BB), 512, 0, stream>>>(mem, wvalT, wgate, wmaxp, wsump,
                                                        swsc, outm, anp);
    kOut<<<BB, 256, 0, stream>>>(outh, rvec, out_w, out_b, proj_w, proj_b, ln_g, ln_b, outv, anp);
}